// Round 1
// baseline (217.744 us; speedup 1.0000x reference)
//
#include <hip/hip_runtime.h>
#include <hip/hip_bf16.h>
#include <math.h>

#define B_ROWS 16384
#define C_COLS 1000
#define C_PAD  1024
#define FDIM   1024

typedef __attribute__((ext_vector_type(8))) short bf16x8;
typedef __attribute__((ext_vector_type(4))) float f32x4;

// async global->LDS, 16B per lane; lds dst must be wave-uniform base (HW puts lane i at base + i*16)
#define GLD_LDS(gp, lp) __builtin_amdgcn_global_load_lds( \
    (__attribute__((address_space(1))) void*)(gp),        \
    (__attribute__((address_space(3))) void*)(lp), 16, 0, 0)

// ---------------- row L2-normalize fp32 -> bf16 (one block per row) ----------------
__global__ __launch_bounds__(256) void normalize_rows(
    const float* __restrict__ in, __hip_bfloat16* __restrict__ out, int nrows_valid)
{
    const int row = blockIdx.x;
    const int tid = threadIdx.x;
    __shared__ float red[4];

    if (row >= nrows_valid) {           // zero-pad prototype rows 1000..1023
        ushort4 z = make_ushort4(0, 0, 0, 0);
        ((ushort4*)(out + (size_t)row * FDIM))[tid] = z;
        return;
    }

    float4 v = ((const float4*)(in + (size_t)row * FDIM))[tid];
    float ss = v.x * v.x + v.y * v.y + v.z * v.z + v.w * v.w;
    #pragma unroll
    for (int off = 1; off < 64; off <<= 1) ss += __shfl_xor(ss, off, 64);
    const int lane = tid & 63, wave = tid >> 6;
    if (lane == 0) red[wave] = ss;
    __syncthreads();
    const float tot = red[0] + red[1] + red[2] + red[3];
    const float inv = 1.0f / sqrtf(fmaxf(tot, 1e-24f));   // norm >> eps always here

    __hip_bfloat16 o[4];
    o[0] = __float2bfloat16(v.x * inv);
    o[1] = __float2bfloat16(v.y * inv);
    o[2] = __float2bfloat16(v.z * inv);
    o[3] = __float2bfloat16(v.w * inv);
    *((ushort4*)(out + (size_t)row * FDIM + tid * 4)) = *(ushort4*)o;
}

// ---------------- bf16 GEMM (both operands [rows, K]) + distance epilogue ----------------
// A: [16384,1024] normalized features (bf16)
// Bp: [1024,1024] normalized prototypes (bf16, rows >=1000 zeroed)
// D:  [16384,1000] fp32 distances; rowsum: [16384] fp32 (atomic)
__global__ __launch_bounds__(256) void gemm_dist(
    const __hip_bfloat16* __restrict__ A,
    const __hip_bfloat16* __restrict__ Bp,
    float* __restrict__ D,
    float* __restrict__ rowsum)
{
    __shared__ __hip_bfloat16 As[128 * 32];   // [row][k] row-major, 64B rows
    __shared__ __hip_bfloat16 Bs[128 * 32];

    const int tid  = threadIdx.x;
    const int lane = tid & 63;
    const int wave = tid >> 6;
    const int bm = blockIdx.y;      // 0..127
    const int bn = blockIdx.x;      // 0..7
    const int waveM = (wave >> 1) * 64;
    const int waveN = (wave & 1) * 64;

    f32x4 acc[4][4] = {};

    // staging lane mapping: chunk = 16 rows * 32 k (1 KiB); lane i -> row i>>2, k-offset (i&3)*8
    const int srow  = lane >> 2;
    const int skoff = (lane & 3) * 8;
    const __hip_bfloat16* Abase = A  + (size_t)(bm * 128) * FDIM;
    const __hip_bfloat16* Bbase = Bp + (size_t)(bn * 128) * FDIM;

    #pragma unroll 1
    for (int k0 = 0; k0 < FDIM; k0 += 32) {
        __syncthreads();
        #pragma unroll
        for (int c = 0; c < 2; ++c) {
            const int chunk = wave * 2 + c;          // 0..7
            const int row = chunk * 16 + srow;
            GLD_LDS(Abase + (size_t)row * FDIM + k0 + skoff, &As[chunk * 16 * 32]);
            GLD_LDS(Bbase + (size_t)row * FDIM + k0 + skoff, &Bs[chunk * 16 * 32]);
        }
        __syncthreads();

        bf16x8 a[4], b[4];
        #pragma unroll
        for (int mt = 0; mt < 4; ++mt)
            a[mt] = *(const bf16x8*)&As[(waveM + mt * 16 + (lane & 15)) * 32 + (lane >> 4) * 8];
        #pragma unroll
        for (int nt = 0; nt < 4; ++nt)
            b[nt] = *(const bf16x8*)&Bs[(waveN + nt * 16 + (lane & 15)) * 32 + (lane >> 4) * 8];

        #pragma unroll
        for (int mt = 0; mt < 4; ++mt)
            #pragma unroll
            for (int nt = 0; nt < 4; ++nt)
                acc[mt][nt] = __builtin_amdgcn_mfma_f32_16x16x32_bf16(a[mt], b[nt], acc[mt][nt], 0, 0, 0);
    }

    // epilogue: d = sqrt(max(1 - sim, 0)); C/D layout: col = lane&15, row = (lane>>4)*4 + reg
    const int row0 = bm * 128 + waveM;
    const int col0 = bn * 128 + waveN;
    #pragma unroll
    for (int mt = 0; mt < 4; ++mt) {
        #pragma unroll
        for (int r = 0; r < 4; ++r) {
            const int row = row0 + mt * 16 + (lane >> 4) * 4 + r;
            float part = 0.0f;
            #pragma unroll
            for (int nt = 0; nt < 4; ++nt) {
                const int col = col0 + nt * 16 + (lane & 15);
                const float sim = acc[mt][nt][r];
                const float dv = sqrtf(fmaxf(1.0f - sim, 0.0f));
                if (col < C_COLS) {
                    D[(size_t)row * C_COLS + col] = dv;
                    part += dv;
                }
            }
            part += __shfl_xor(part, 1, 64);
            part += __shfl_xor(part, 2, 64);
            part += __shfl_xor(part, 4, 64);
            part += __shfl_xor(part, 8, 64);
            if ((lane & 15) == 0) atomicAdd(&rowsum[row], part);
        }
    }
}

// ---------------- finalize: out = (-|ds|/T) * (d + rowsum/1000) ----------------
__global__ __launch_bounds__(256) void finalize(
    const float* __restrict__ D, const float* __restrict__ rowsum,
    const float* __restrict__ scale, const float* __restrict__ temp,
    float* __restrict__ out)
{
    const size_t i = (size_t)blockIdx.x * blockDim.x + threadIdx.x;  // float4 index
    const float a = -fabsf(scale[0]) / temp[0];
    const int b = (int)((i * 4) / C_COLS);        // 1000 % 4 == 0 -> float4 never straddles rows
    const float m = rowsum[b] * (1.0f / (float)C_COLS);
    float4 dv = ((const float4*)D)[i];
    float4 o;
    o.x = a * (dv.x + m);
    o.y = a * (dv.y + m);
    o.z = a * (dv.z + m);
    o.w = a * (dv.w + m);
    ((float4*)out)[i] = o;
}

extern "C" void kernel_launch(void* const* d_in, const int* in_sizes, int n_in,
                              void* d_out, int out_size, void* d_ws, size_t ws_size,
                              hipStream_t stream)
{
    const float* features = (const float*)d_in[0];   // [16384,1024]
    const float* protos   = (const float*)d_in[1];   // [1000,1024]
    const float* dscale   = (const float*)d_in[2];   // [1]
    const float* temp     = (const float*)d_in[3];   // [1]
    float* out = (float*)d_out;                      // [16384,1000]

    char* ws = (char*)d_ws;
    __hip_bfloat16* fb = (__hip_bfloat16*)ws;                         // 33,554,432 B
    __hip_bfloat16* pb = (__hip_bfloat16*)(ws + 33554432);            //  2,097,152 B
    float* D      = (float*)(ws + 35651584);                          // 65,536,000 B
    float* rowsum = (float*)(ws + 101187584);                         //     65,536 B

    hipMemsetAsync(rowsum, 0, B_ROWS * sizeof(float), stream);

    normalize_rows<<<B_ROWS, 256, 0, stream>>>(features, fb, B_ROWS);
    normalize_rows<<<C_PAD,  256, 0, stream>>>(protos,   pb, C_COLS);

    dim3 g(8, 128);
    gemm_dist<<<g, 256, 0, stream>>>(fb, pb, D, rowsum);

    finalize<<<(B_ROWS * C_COLS / 4) / 256, 256, 0, stream>>>(D, rowsum, dscale, temp, out);
}

// Round 2
// 186.091 us; speedup vs baseline: 1.1701x; 1.1701x over previous
//
#include <hip/hip_runtime.h>
#include <hip/hip_bf16.h>
#include <math.h>

#define B_ROWS 16384
#define C_COLS 1000
#define C_PAD  1024
#define FDIM   1024

typedef __attribute__((ext_vector_type(8))) short bf16x8;
typedef __attribute__((ext_vector_type(4))) float f32x4;

// async global->LDS, 16B per lane; lds dst is wave-uniform base (HW puts lane i at base + i*16)
#define GLD_LDS(gp, lp) __builtin_amdgcn_global_load_lds( \
    (__attribute__((address_space(1))) void*)(gp),        \
    (__attribute__((address_space(3))) void*)(lp), 16, 0, 0)

// ---------------- row L2-normalize fp32 -> bf16 (one wave per row, 4 rows/block) ----------------
__global__ __launch_bounds__(256) void normalize_rows(
    const float* __restrict__ in, __hip_bfloat16* __restrict__ out, int nrows_valid)
{
    const int lane = threadIdx.x & 63;
    const int wave = threadIdx.x >> 6;
    const int row  = blockIdx.x * 4 + wave;
    __hip_bfloat16* orow = out + (size_t)row * FDIM;

    if (row >= nrows_valid) {           // zero-pad prototype rows 1000..1023
        ushort4 z = make_ushort4(0, 0, 0, 0);
        #pragma unroll
        for (int c = 0; c < 4; ++c) ((ushort4*)orow)[lane + c * 64] = z;
        return;
    }

    const float4* rp = (const float4*)(in + (size_t)row * FDIM);
    float4 v[4];
    float ss = 0.0f;
    #pragma unroll
    for (int c = 0; c < 4; ++c) {
        v[c] = rp[lane + c * 64];
        ss += v[c].x * v[c].x + v[c].y * v[c].y + v[c].z * v[c].z + v[c].w * v[c].w;
    }
    #pragma unroll
    for (int off = 1; off < 64; off <<= 1) ss += __shfl_xor(ss, off, 64);
    const float inv = 1.0f / sqrtf(fmaxf(ss, 1e-24f));

    #pragma unroll
    for (int c = 0; c < 4; ++c) {
        __hip_bfloat16 o[4];
        o[0] = __float2bfloat16(v[c].x * inv);
        o[1] = __float2bfloat16(v[c].y * inv);
        o[2] = __float2bfloat16(v[c].z * inv);
        o[3] = __float2bfloat16(v[c].w * inv);
        ((ushort4*)orow)[lane + c * 64] = *(ushort4*)o;
    }
}

// ---------------- bf16 GEMM (both operands [rows, K]) + distance epilogue ----------------
// LDS layout: tile [128 rows][64 k], row stride = 64 elems (128 B = all 32 banks).
// Within a row, 8 phys slots of 8 elems (16 B); logical ksub k stored at slot (k ^ (row&7))
// -> ds_read_b128 bank-starts cover all 8 quad offsets => 2-way (free).
__global__ __launch_bounds__(256) void gemm_dist(
    const __hip_bfloat16* __restrict__ A,
    const __hip_bfloat16* __restrict__ Bp,
    __hip_bfloat16* __restrict__ D,
    float* __restrict__ rowsum)
{
    __shared__ __hip_bfloat16 As[128 * 64];   // 16 KB
    __shared__ __hip_bfloat16 Bs[128 * 64];   // 16 KB

    const int tid  = threadIdx.x;
    const int lane = tid & 63;
    const int wave = tid >> 6;

    // XCD swizzle: all 8 bn-blocks of one bm share id%8 (same XCD) for A-tile L2 reuse
    const int id  = blockIdx.x;          // 0..1023
    const int xcd = id & 7;
    const int seq = id >> 3;             // 0..127
    const int bn  = seq & 7;             // 0..7
    const int bm  = xcd * 16 + (seq >> 3);  // 0..127

    const int waveM = (wave >> 1) * 64;
    const int waveN = (wave & 1) * 64;

    f32x4 acc[4][4] = {};

    // staging: chunk = 8 rows x 64 k (1 KB); lane i -> row i>>3, phys slot i&7,
    // fetches logical ksub = (i&7) ^ ((i>>3)&7)
    const int srow  = lane >> 3;
    const int sksub = (lane & 7) ^ (srow & 7);
    const __hip_bfloat16* Abase = A  + ((size_t)(bm * 128) + srow) * FDIM + sksub * 8;
    const __hip_bfloat16* Bbase = Bp + ((size_t)(bn * 128) + srow) * FDIM + sksub * 8;

    #pragma unroll 1
    for (int k0 = 0; k0 < FDIM; k0 += 64) {
        __syncthreads();
        #pragma unroll
        for (int c4 = 0; c4 < 4; ++c4) {
            const int chunk = wave * 4 + c4;               // 0..15
            GLD_LDS(Abase + (size_t)(chunk * 8) * FDIM + k0, &As[chunk * 512]);
            GLD_LDS(Bbase + (size_t)(chunk * 8) * FDIM + k0, &Bs[chunk * 512]);
        }
        __syncthreads();

        #pragma unroll
        for (int h = 0; h < 2; ++h) {
            bf16x8 a[4], b[4];
            const int q = h * 4 + (lane >> 4);             // logical ksub 0..7
            #pragma unroll
            for (int mt = 0; mt < 4; ++mt) {
                const int R = waveM + mt * 16 + (lane & 15);
                a[mt] = *(const bf16x8*)&As[R * 64 + ((q ^ (R & 7)) * 8)];
            }
            #pragma unroll
            for (int nt = 0; nt < 4; ++nt) {
                const int R = waveN + nt * 16 + (lane & 15);
                b[nt] = *(const bf16x8*)&Bs[R * 64 + ((q ^ (R & 7)) * 8)];
            }
            #pragma unroll
            for (int mt = 0; mt < 4; ++mt)
                #pragma unroll
                for (int nt = 0; nt < 4; ++nt)
                    acc[mt][nt] = __builtin_amdgcn_mfma_f32_16x16x32_bf16(a[mt], b[nt], acc[mt][nt], 0, 0, 0);
        }
    }

    // epilogue: d = sqrt(max(1 - sim, 0)); C/D layout: col = lane&15, row = (lane>>4)*4 + reg
    const int row0 = bm * 128 + waveM;
    const int col0 = bn * 128 + waveN;
    #pragma unroll
    for (int mt = 0; mt < 4; ++mt) {
        #pragma unroll
        for (int r = 0; r < 4; ++r) {
            const int row = row0 + mt * 16 + (lane >> 4) * 4 + r;
            float part = 0.0f;
            #pragma unroll
            for (int nt = 0; nt < 4; ++nt) {
                const int col = col0 + nt * 16 + (lane & 15);
                const float sim = acc[mt][nt][r];
                const float dv = sqrtf(fmaxf(1.0f - sim, 0.0f));
                if (col < C_COLS) {
                    D[(size_t)row * C_COLS + col] = __float2bfloat16(dv);
                    part += dv;
                }
            }
            part += __shfl_xor(part, 1, 64);
            part += __shfl_xor(part, 2, 64);
            part += __shfl_xor(part, 4, 64);
            part += __shfl_xor(part, 8, 64);
            if ((lane & 15) == 0) atomicAdd(&rowsum[row], part);
        }
    }
}

// ---------------- finalize: out = (-|ds|/T) * (d + rowsum/1000) ----------------
__global__ __launch_bounds__(256) void finalize(
    const __hip_bfloat16* __restrict__ D, const float* __restrict__ rowsum,
    const float* __restrict__ scale, const float* __restrict__ temp,
    float* __restrict__ out)
{
    const size_t i = (size_t)blockIdx.x * 256 + threadIdx.x;   // 8-element group
    const float a = -fabsf(scale[0]) / temp[0];
    const int row = (int)((i * 8) / C_COLS);                   // 1000 % 8 == 0, no straddle
    const float m = rowsum[row] * (1.0f / (float)C_COLS);

    const bf16x8 dv = *(const bf16x8*)(D + i * 8);
    const __hip_bfloat16* dp = (const __hip_bfloat16*)&dv;
    float4 o0, o1;
    o0.x = a * (__bfloat162float(dp[0]) + m);
    o0.y = a * (__bfloat162float(dp[1]) + m);
    o0.z = a * (__bfloat162float(dp[2]) + m);
    o0.w = a * (__bfloat162float(dp[3]) + m);
    o1.x = a * (__bfloat162float(dp[4]) + m);
    o1.y = a * (__bfloat162float(dp[5]) + m);
    o1.z = a * (__bfloat162float(dp[6]) + m);
    o1.w = a * (__bfloat162float(dp[7]) + m);
    ((float4*)out)[i * 2]     = o0;
    ((float4*)out)[i * 2 + 1] = o1;
}

extern "C" void kernel_launch(void* const* d_in, const int* in_sizes, int n_in,
                              void* d_out, int out_size, void* d_ws, size_t ws_size,
                              hipStream_t stream)
{
    const float* features = (const float*)d_in[0];   // [16384,1024]
    const float* protos   = (const float*)d_in[1];   // [1000,1024]
    const float* dscale   = (const float*)d_in[2];   // [1]
    const float* temp     = (const float*)d_in[3];   // [1]
    float* out = (float*)d_out;                      // [16384,1000]

    char* ws = (char*)d_ws;
    __hip_bfloat16* fb = (__hip_bfloat16*)ws;                     // 33,554,432 B
    __hip_bfloat16* pb = (__hip_bfloat16*)(ws + 33554432);        //  2,097,152 B
    __hip_bfloat16* D  = (__hip_bfloat16*)(ws + 35651584);        // 32,768,000 B
    float* rowsum      = (float*)(ws + 68419584);                 //     65,536 B

    hipMemsetAsync(rowsum, 0, B_ROWS * sizeof(float), stream);

    normalize_rows<<<B_ROWS / 4, 256, 0, stream>>>(features, fb, B_ROWS);
    normalize_rows<<<C_PAD / 4,  256, 0, stream>>>(protos,   pb, C_COLS);

    gemm_dist<<<1024, 256, 0, stream>>>(fb, pb, D, rowsum);

    finalize<<<(B_ROWS * C_COLS / 8) / 256, 256, 0, stream>>>(D, rowsum, dscale, temp, out);
}